// Round 11
// baseline (166.152 us; speedup 1.0000x reference)
//
#include <hip/hip_runtime.h>

typedef __bf16 bf16;
typedef __bf16 bf16x8 __attribute__((ext_vector_type(8)));
typedef float  f32x4  __attribute__((ext_vector_type(4)));

// Problem constants
#define NSPEC   512          // 256 pairs * 2
#define BOUT    9999         // GROUPS*3
#define K0A     10240        // BOUT padded to 16*10*64 (ksplit*kiters*BK)
#define N00     1024         // 1000 padded
#define KSPLIT0 16

// async global->LDS, 16B per lane; lds base must be wave-uniform (HW adds lane*16)
__device__ __forceinline__ void gload_lds16(const bf16* g, bf16* l) {
    auto* gp = reinterpret_cast<const __attribute__((address_space(1))) unsigned int*>(
        reinterpret_cast<uintptr_t>(g));
    auto* lp = reinterpret_cast<__attribute__((address_space(3))) unsigned int*>(
        reinterpret_cast<uintptr_t>(l));
    __builtin_amdgcn_global_load_lds(gp, lp, 16, 0, 0);
}

// ---------------- transpose helper: 64(n) x 32(k) tile, 512 threads ----------------
__device__ __forceinline__ void transpose_tile64(const float* __restrict__ src,
                                                 bf16* __restrict__ dst,
                                                 int K, int N, int K0,
                                                 float* tile, int bx, int by) {
    int n0 = bx * 64, k0 = by * 32;
    int t = threadIdx.x;
    {
        int kr = t >> 4, nc = (t & 15) * 4;          // 32 rows x 64 cols
        int gk = k0 + kr;
#pragma unroll
        for (int e = 0; e < 4; ++e) {
            int gn = n0 + nc + e;
            tile[kr * 65 + nc + e] = (gk < K && gn < N) ? src[(size_t)gk * N + gn] : 0.0f;
        }
    }
    __syncthreads();
    {
        int nr = t >> 3, kc = (t & 7) * 4;           // 64 n-rows x 32 k-cols
        bf16 v[4];
#pragma unroll
        for (int e = 0; e < 4; ++e) v[e] = (bf16)tile[(kc + e) * 65 + nr];
        *(ushort4*)&dst[(size_t)(n0 + nr) * K0 + k0 + kc] = *(ushort4*)v;
    }
}

// ---------------- prep_A: w0 transpose + build_A (only what gemm0 needs) ----------------
__global__ __launch_bounds__(512) void prep_A(const float* __restrict__ mz,
                                              const float* __restrict__ inten,
                                              const float* __restrict__ bw,
                                              const float* __restrict__ bb,
                                              const float* __restrict__ w0,
                                              bf16* __restrict__ A,
                                              bf16* __restrict__ B0t) {
    __shared__ float smem[K0A];    // 40 KB: sacc for build_A, tile[32*65] for transpose
    int b = blockIdx.x;
    if (b < 5120) {                       // w0 -> B0t (1024 x 10240): 16 x 320 tiles
        transpose_tile64(w0, B0t, BOUT, 1000, K0A, smem, b & 15, b >> 4);
    } else {                              // build_A: one block per spectrum
        const int spec = b - 5120;
        const int t = threadIdx.x;
#pragma unroll
        for (int i = 0; i < 5; ++i)
            *(float4*)&smem[(i * 512 + t) * 4] = float4{0.f, 0.f, 0.f, 0.f};
        __syncthreads();
        {
            float m = mz[(size_t)spec * 512 + t];
            float v = inten[(size_t)spec * 512 + t];
            bool mask = (m >= 0.0f) && (m < 1000.0f);
            int idx = (int)(m / 0.01f);       // IEEE div + trunc, matches astype(int32)
            idx = min(max(idx, 0), 99999);
            if (mask && idx < 99990) {
                int g = idx / 30;
                float val = sqrtf(v);         // inten ** 0.5
                const float* w = bw + (size_t)idx * 3;
                atomicAdd(&smem[g * 3 + 0], val * w[0]);
                atomicAdd(&smem[g * 3 + 1], val * w[1]);
                atomicAdd(&smem[g * 3 + 2], val * w[2]);
            }
        }
        __syncthreads();
        bf16* Arow = A + (size_t)spec * K0A;
#pragma unroll
        for (int i = 0; i < 5; ++i) {
            int c = (i * 512 + t) * 4;
            float4 s = *(const float4*)&smem[c];
            bf16 o[4];
            o[0] = (bf16)((c + 0 < BOUT) ? bb[c + 0] + s.x : 0.f);
            o[1] = (bf16)((c + 1 < BOUT) ? bb[c + 1] + s.y : 0.f);
            o[2] = (bf16)((c + 2 < BOUT) ? bb[c + 2] + s.z : 0.f);
            o[3] = (bf16)((c + 3 < BOUT) ? bb[c + 3] + s.w : 0.f);
            *(ushort4*)&Arow[c] = *(ushort4*)o;
        }
    }
}

// ---------------- GEMM0 (+aux): 128x128xBK64, 512 thr, split-K=16 XCD-pinned, dbuf, swizzled ----
// bid < 512: GEMM blocks (scheduled first, fill all CU slots at 2 blocks/CU).
// bid >= 512: aux blocks (tail-weight transposes, pad zeroing, psums zero) — no dependency on
// the GEMM inputs; they backfill CUs as GEMM blocks retire. Their outputs are consumed only by
// later launches (stream-ordered), so no intra-kernel ordering is needed.
__global__ __launch_bounds__(512) void gemm0_splitk(const bf16* __restrict__ A,
                                                    const bf16* __restrict__ Bt,
                                                    bf16* __restrict__ Cslab,
                                                    const float* __restrict__ w1,
                                                    const float* __restrict__ w2,
                                                    const float* __restrict__ we,
                                                    bf16* __restrict__ B1t,
                                                    bf16* __restrict__ B2t,
                                                    bf16* __restrict__ BEt,
                                                    bf16* __restrict__ H1b,
                                                    bf16* __restrict__ H2b,
                                                    float* __restrict__ psums) {
    constexpr int K0 = K0A, KITERS = 10, BK = 64;
    __shared__ __align__(16) bf16 As[2][128 * BK];   // 16 KB each buf
    __shared__ __align__(16) bf16 Bs[2][128 * BK];   // 16 KB each buf
    const int bid = blockIdx.x;
    if (bid >= 512) {                     // ---- aux blocks ----
        int r = bid - 512;
        float* tile = (float*)&As[0][0];  // reuse LDS
        if (r < 448)        transpose_tile64(w1, B1t, 1000, 800, 1024, tile, r % 14, r / 14);
        else if (r < 896)  { r -= 448;  transpose_tile64(w2, B2t, 800, 800, 1024, tile, r % 14, r / 14); }
        else if (r < 1120) { r -= 896;  transpose_tile64(we, BEt, 800, 400, 1024, tile, r % 7,  r / 7); }
        else if (r < 1152) {              // zero K-pad cols 896..1023 of H1b/H2b
            int idx = r - 1120;           // 0..31
            bf16* H = (idx < 16) ? H1b : H2b;
            int sub = idx & 15;
            int t = threadIdx.x;
            int row = sub * 32 + (t >> 4);
            int col = 896 + (t & 15) * 8;
            *(uint4*)&H[(size_t)row * 1024 + col] = uint4{0u, 0u, 0u, 0u};
        } else {                          // zero cosine accumulators
            for (int i = threadIdx.x; i < 768; i += 512) psums[i] = 0.f;
        }
        return;
    }
    // ---- GEMM blocks ----
    const int kp = bid & 15;                  // XCD = bid%8 hosts kp, kp+8 -> ~3.8 MB L2 footprint
    const int tile = bid >> 4;                // 0..31
    const int mt = tile & 3, nt = tile >> 2;  // 4 x 8
    const int tid = threadIdx.x, wave = tid >> 6, lane = tid & 63;
    const int wm = wave & 1, wn = wave >> 1;  // 2x4 wave grid: 64m x 32n per wave
    const int lrow = lane & 15, quad = lane >> 4;

    const bf16* Ag = A  + (size_t)(mt * 128) * K0 + kp * (KITERS * BK);
    const bf16* Bg = Bt + (size_t)(nt * 128) * K0 + kp * (KITERS * BK);

    auto stage = [&](int buf, int kk) {
        const int k = kk * BK;
        const int lr = lane >> 3;                      // lane's row within an 8-row group
        const int lch = lane & 7;
#pragma unroll
        for (int j = 0; j < 2; ++j) {                  // A: 128 rows in 2 calls/wave (8 rows/call)
            int row0 = j * 64 + wave * 8;
            int row = row0 + lr;
            int ch  = lch ^ (row & 7);
            gload_lds16(Ag + (size_t)row * K0 + k + ch * 8, &As[buf][row0 * BK]);
        }
#pragma unroll
        for (int j = 0; j < 2; ++j) {                  // B: 128 rows in 2 calls/wave
            int row0 = j * 64 + wave * 8;
            int row = row0 + lr;
            int ch  = lch ^ (row & 7);
            gload_lds16(Bg + (size_t)row * K0 + k + ch * 8, &Bs[buf][row0 * BK]);
        }
    };

    f32x4 acc[4][2] = {};
    stage(0, 0);
    for (int kk = 0; kk < KITERS; ++kk) {
        const int cur = kk & 1;
        __syncthreads();                      // buf[cur] drained (vmcnt0 at barrier)
        if (kk + 1 < KITERS) stage(cur ^ 1, kk + 1);  // prefetch overlaps compute
#pragma unroll
        for (int ks = 0; ks < 2; ++ks) {
            bf16x8 af[4], bfr[2];
            const int c = ks * 4 + quad;
#pragma unroll
            for (int im = 0; im < 4; ++im) {
                int r = wm * 64 + im * 16 + lrow;
                af[im] = *(const bf16x8*)&As[cur][r * BK + ((c ^ (r & 7)) << 3)];
            }
#pragma unroll
            for (int in = 0; in < 2; ++in) {
                int r = wn * 32 + in * 16 + lrow;
                bfr[in] = *(const bf16x8*)&Bs[cur][r * BK + ((c ^ (r & 7)) << 3)];
            }
#pragma unroll
            for (int im = 0; im < 4; ++im)
#pragma unroll
                for (int in = 0; in < 2; ++in)
                    acc[im][in] = __builtin_amdgcn_mfma_f32_16x16x32_bf16(af[im], bfr[in], acc[im][in], 0, 0, 0);
        }
    }
    // bf16 partial stores into this kp's slab — no atomics, no fences
    bf16* C = Cslab + (size_t)kp * (NSPEC * N00);
#pragma unroll
    for (int im = 0; im < 4; ++im) {
        int row0 = mt * 128 + wm * 64 + im * 16 + quad * 4;
#pragma unroll
        for (int in = 0; in < 2; ++in) {
            int col = nt * 128 + wn * 32 + in * 16 + lrow;
#pragma unroll
            for (int r = 0; r < 4; ++r)
                C[(size_t)(row0 + r) * N00 + col] = (bf16)acc[im][in][r];
        }
    }
}

// ---------------- reduce 16 bf16 slabs + bias + relu + bf16 cvt ----------------
__global__ __launch_bounds__(256) void reduce_bias_relu(const bf16* __restrict__ Cslab,
                                                        const float* __restrict__ b0,
                                                        bf16* __restrict__ H0b) {
    int idx = blockIdx.x * 256 + threadIdx.x;     // 65536 chunks of 8
    int r = idx >> 7, c = (idx & 127) * 8;
    float s[8] = {};
#pragma unroll
    for (int kp = 0; kp < KSPLIT0; ++kp) {
        bf16x8 v = *(const bf16x8*)&Cslab[(size_t)kp * (NSPEC * N00) + (size_t)r * N00 + c];
#pragma unroll
        for (int j = 0; j < 8; ++j) s[j] += (float)v[j];
    }
    bf16 o[8];
#pragma unroll
    for (int j = 0; j < 8; ++j)
        o[j] = (bf16)fmaxf(s[j] + ((c + j < 1000) ? b0[c + j] : 0.f), 0.f);
    *(uint4*)&H0b[(size_t)r * N00 + c] = *(uint4*)o;
}

// ---------------- tail GEMM: 32x32 tiles, 512 thr, BK=256, wave-split-K, dbuf, swizzled ----------------
template <bool LAST>
__global__ __launch_bounds__(512) void gemm_tail(const bf16* __restrict__ A,
                                                 const bf16* __restrict__ Bt,
                                                 const float* __restrict__ bias,
                                                 bf16* __restrict__ Ob,
                                                 float* __restrict__ psums,
                                                 int Nreal, int ntiles) {
    constexpr int BK = 256, KITERS = 4;
    __shared__ __align__(16) bf16 As[2][32 * BK];   // 16 KB each
    __shared__ __align__(16) bf16 Bs[2][32 * BK];
    __shared__ f32x4 xacc[4][64];                   // 4 KB cross-wave combine
    const int bid = blockIdx.x;
    const int mt = bid / ntiles, nt = bid % ntiles;
    const int tid = threadIdx.x, wave = tid >> 6, lane = tid & 63;
    const int g = wave >> 2, w2 = wave & 3;
    const int wm = w2 & 1, wn = w2 >> 1;
    const int lrow = lane & 15, quad = lane >> 4;

    const bf16* Ag = A  + (size_t)(mt * 32) * 1024;
    const bf16* Bg = Bt + (size_t)(nt * 32) * 1024;

    auto stage = [&](int buf, int kk) {
        const int k = kk * BK;
#pragma unroll
        for (int j = 0; j < 2; ++j) {
            int row0 = (wave + j * 8) * 2;             // wave-uniform; covers rows row0, row0+1
            int row = row0 + (lane >> 5);
            int ch  = (lane & 31) ^ (row & 31);        // swizzled source chunk (32 chunks/row)
            gload_lds16(Ag + (size_t)row * 1024 + k + ch * 8, &As[buf][row0 * BK]);
            gload_lds16(Bg + (size_t)row * 1024 + k + ch * 8, &Bs[buf][row0 * BK]);
        }
    };

    f32x4 acc = {};
    stage(0, 0);
    for (int kk = 0; kk < KITERS; ++kk) {
        const int cur = kk & 1;
        __syncthreads();
        if (kk + 1 < KITERS) stage(cur ^ 1, kk + 1);
#pragma unroll
        for (int ks = 0; ks < 4; ++ks) {
            int ra = wm * 16 + lrow, rb = wn * 16 + lrow;
            int c = g * 16 + ks * 4 + quad;            // group g takes its k-half
            bf16x8 af  = *(const bf16x8*)&As[cur][ra * BK + ((c ^ (ra & 31)) << 3)];
            bf16x8 bfr = *(const bf16x8*)&Bs[cur][rb * BK + ((c ^ (rb & 31)) << 3)];
            acc = __builtin_amdgcn_mfma_f32_16x16x32_bf16(af, bfr, acc, 0, 0, 0);
        }
    }
    // combine the two k-halves
    __syncthreads();
    if (g == 1) xacc[w2][lane] = acc;
    __syncthreads();
    if (g == 0) {
        f32x4 o = xacc[w2][lane];
        acc[0] += o[0]; acc[1] += o[1]; acc[2] += o[2]; acc[3] += o[3];
        int row0 = mt * 32 + wm * 16 + quad * 4;
        int col  = nt * 32 + wn * 16 + lrow;
        if (!LAST) {
            float bv = (col < Nreal) ? bias[col] : 0.f;
#pragma unroll
            for (int r = 0; r < 4; ++r)
                Ob[(size_t)(row0 + r) * 1024 + col] = (bf16)fmaxf(acc[r] + bv, 0.f);
        } else {
            bool valid = (col < 400);
            float bv = valid ? bias[col] : 0.f;
            float v[4];
#pragma unroll
            for (int r = 0; r < 4; ++r) v[r] = valid ? (acc[r] + bv) : 0.f;
            int p0 = row0 >> 1;                        // pairs p0, p0+1 (row0 even)
            float sums[6] = {v[0] * v[1], v[0] * v[0], v[1] * v[1],
                             v[2] * v[3], v[2] * v[2], v[3] * v[3]};
#pragma unroll
            for (int off = 1; off < 16; off <<= 1)
#pragma unroll
                for (int s = 0; s < 6; ++s) sums[s] += __shfl_xor(sums[s], off);
            if (lrow == 0) {
#pragma unroll
                for (int s = 0; s < 3; ++s) {
                    atomicAdd(&psums[(p0 + 0) * 3 + s], sums[s]);
                    atomicAdd(&psums[(p0 + 1) * 3 + s], sums[3 + s]);
                }
            }
        }
    }
}

// ---------------- finalize cosine from psums ----------------
__global__ __launch_bounds__(256) void cosine_fin(const float* __restrict__ psums,
                                                  float* __restrict__ out) {
    int t = threadIdx.x;
    float d  = psums[t * 3 + 0];
    float s1 = psums[t * 3 + 1];
    float s2 = psums[t * 3 + 2];
    float n1 = fmaxf(sqrtf(s1), 1e-6f);
    float n2 = fmaxf(sqrtf(s2), 1e-6f);
    out[t] = d / (n1 * n2);
}

extern "C" void kernel_launch(void* const* d_in, const int* in_sizes, int n_in,
                              void* d_out, int out_size, void* d_ws, size_t ws_size,
                              hipStream_t stream) {
    const float* mz    = (const float*)d_in[0];
    const float* inten = (const float*)d_in[1];
    const float* bw    = (const float*)d_in[2];
    const float* bb    = (const float*)d_in[3];
    const float* w0    = (const float*)d_in[4];
    const float* b0    = (const float*)d_in[5];
    const float* w1    = (const float*)d_in[6];
    const float* b1    = (const float*)d_in[7];
    const float* w2    = (const float*)d_in[8];
    const float* b2    = (const float*)d_in[9];
    const float* we    = (const float*)d_in[10];
    const float* be    = (const float*)d_in[11];
    float* out = (float*)d_out;

    char* ws = (char*)d_ws;
    size_t off = 0;
    auto alloc = [&](size_t bytes) { char* p = ws + off; off += (bytes + 255) & ~(size_t)255; return p; };
    bf16*  A     = (bf16*) alloc((size_t)NSPEC * K0A * 2);
    bf16*  B0t   = (bf16*) alloc((size_t)N00 * K0A * 2);
    bf16*  B1t   = (bf16*) alloc((size_t)896 * 1024 * 2);
    bf16*  B2t   = (bf16*) alloc((size_t)896 * 1024 * 2);
    bf16*  BEt   = (bf16*) alloc((size_t)448 * 1024 * 2);
    bf16*  Cslab = (bf16*) alloc((size_t)KSPLIT0 * NSPEC * N00 * 2);   // 16 MB
    bf16*  H0b   = (bf16*) alloc((size_t)NSPEC * 1024 * 2);
    bf16*  H1b   = (bf16*) alloc((size_t)NSPEC * 1024 * 2);
    bf16*  H2b   = (bf16*) alloc((size_t)NSPEC * 1024 * 2);
    float* psums = (float*)alloc(768 * 4);

    // 1: w0 transpose + build_A (critical path for gemm0 only)
    prep_A<<<5632, 512, 0, stream>>>(mz, inten, bw, bb, w0, A, B0t);
    // 2: big GEMM (512 blocks) + aux tail-prep blocks (1153) backfilling retiring CUs
    gemm0_splitk<<<1665, 512, 0, stream>>>(A, B0t, Cslab,
                                           w1, w2, we, B1t, B2t, BEt, H1b, H2b, psums);
    // 3: slab reduce + bias + relu + bf16 cvt
    reduce_bias_relu<<<256, 256, 0, stream>>>(Cslab, b0, H0b);
    // 4-5: tail GEMMs, wave-split-K (bias+relu+bf16 fused)
    gemm_tail<false><<<448, 512, 0, stream>>>(H0b, B1t, b1, H1b, nullptr, 800, 28);
    gemm_tail<false><<<448, 512, 0, stream>>>(H1b, B2t, b2, H2b, nullptr, 800, 28);
    // 6: last GEMM + cosine partials (plain atomics, no fences)
    gemm_tail<true ><<<224, 512, 0, stream>>>(H2b, BEt, be, nullptr, psums, 400, 14);
    // 7: finalize
    cosine_fin<<<1, 256, 0, stream>>>(psums, out);
}

// Round 12
// 162.001 us; speedup vs baseline: 1.0256x; 1.0256x over previous
//
#include <hip/hip_runtime.h>

typedef __bf16 bf16;
typedef __bf16 bf16x8 __attribute__((ext_vector_type(8)));
typedef float  f32x4  __attribute__((ext_vector_type(4)));

// Problem constants
#define NSPEC   512          // 256 pairs * 2
#define BOUT    9999         // GROUPS*3
#define K0A     10240        // BOUT padded to 16*10*64 (ksplit*kiters*BK)
#define N00     1024         // 1000 padded
#define KSPLIT0 16

// async global->LDS, 16B per lane; lds base must be wave-uniform (HW adds lane*16)
__device__ __forceinline__ void gload_lds16(const bf16* g, bf16* l) {
    auto* gp = reinterpret_cast<const __attribute__((address_space(1))) unsigned int*>(
        reinterpret_cast<uintptr_t>(g));
    auto* lp = reinterpret_cast<__attribute__((address_space(3))) unsigned int*>(
        reinterpret_cast<uintptr_t>(l));
    __builtin_amdgcn_global_load_lds(gp, lp, 16, 0, 0);
}

// ---------------- transpose helper: 64(n) x 32(k) tile, 512 threads ----------------
__device__ __forceinline__ void transpose_tile64(const float* __restrict__ src,
                                                 bf16* __restrict__ dst,
                                                 int K, int N, int K0,
                                                 float* tile, int bx, int by) {
    int n0 = bx * 64, k0 = by * 32;
    int t = threadIdx.x;
    {
        int kr = t >> 4, nc = (t & 15) * 4;          // 32 rows x 64 cols
        int gk = k0 + kr;
#pragma unroll
        for (int e = 0; e < 4; ++e) {
            int gn = n0 + nc + e;
            tile[kr * 65 + nc + e] = (gk < K && gn < N) ? src[(size_t)gk * N + gn] : 0.0f;
        }
    }
    __syncthreads();
    {
        int nr = t >> 3, kc = (t & 7) * 4;           // 64 n-rows x 32 k-cols
        bf16 v[4];
#pragma unroll
        for (int e = 0; e < 4; ++e) v[e] = (bf16)tile[(kc + e) * 65 + nr];
        *(ushort4*)&dst[(size_t)(n0 + nr) * K0 + k0 + kc] = *(ushort4*)v;
    }
}

// ---------------- mega-prep: weight transposes + build_A + zero pads + zero psums ----------------
__global__ __launch_bounds__(512) void prep_all(const float* __restrict__ mz,
                                                const float* __restrict__ inten,
                                                const float* __restrict__ bw,
                                                const float* __restrict__ bb,
                                                const float* __restrict__ w0,
                                                const float* __restrict__ w1,
                                                const float* __restrict__ w2,
                                                const float* __restrict__ we,
                                                bf16* __restrict__ A,
                                                bf16* __restrict__ B0t,
                                                bf16* __restrict__ B1t,
                                                bf16* __restrict__ B2t,
                                                bf16* __restrict__ BEt,
                                                bf16* __restrict__ H1b,
                                                bf16* __restrict__ H2b,
                                                float* __restrict__ psums) {
    __shared__ float smem[K0A];    // 40 KB: sacc for build_A, tile[32*65] for transposes
    int b = blockIdx.x;
    if (b < 5120) {                       // w0 -> B0t (1024 x 10240): 16 x 320 tiles
        transpose_tile64(w0, B0t, BOUT, 1000, K0A, smem, b & 15, b >> 4);
    } else if (b < 5568) {                // w1 -> B1t (896 x 1024): 14 x 32
        int r = b - 5120;
        transpose_tile64(w1, B1t, 1000, 800, 1024, smem, r % 14, r / 14);
    } else if (b < 6016) {                // w2 -> B2t (896 x 1024): 14 x 32
        int r = b - 5568;
        transpose_tile64(w2, B2t, 800, 800, 1024, smem, r % 14, r / 14);
    } else if (b < 6240) {                // we -> BEt (448 x 1024): 7 x 32
        int r = b - 6016;
        transpose_tile64(we, BEt, 800, 400, 1024, smem, r % 7, r / 7);
    } else if (b < 6752) {                // build_A: one block per spectrum
        const int spec = b - 6240;
        const int t = threadIdx.x;
#pragma unroll
        for (int i = 0; i < 5; ++i)
            *(float4*)&smem[(i * 512 + t) * 4] = float4{0.f, 0.f, 0.f, 0.f};
        __syncthreads();
        {
            float m = mz[(size_t)spec * 512 + t];
            float v = inten[(size_t)spec * 512 + t];
            bool mask = (m >= 0.0f) && (m < 1000.0f);
            int idx = (int)(m / 0.01f);       // IEEE div + trunc, matches astype(int32)
            idx = min(max(idx, 0), 99999);
            if (mask && idx < 99990) {
                int g = idx / 30;
                float val = sqrtf(v);         // inten ** 0.5
                const float* w = bw + (size_t)idx * 3;
                atomicAdd(&smem[g * 3 + 0], val * w[0]);
                atomicAdd(&smem[g * 3 + 1], val * w[1]);
                atomicAdd(&smem[g * 3 + 2], val * w[2]);
            }
        }
        __syncthreads();
        bf16* Arow = A + (size_t)spec * K0A;
#pragma unroll
        for (int i = 0; i < 5; ++i) {
            int c = (i * 512 + t) * 4;
            float4 s = *(const float4*)&smem[c];
            bf16 o[4];
            o[0] = (bf16)((c + 0 < BOUT) ? bb[c + 0] + s.x : 0.f);
            o[1] = (bf16)((c + 1 < BOUT) ? bb[c + 1] + s.y : 0.f);
            o[2] = (bf16)((c + 2 < BOUT) ? bb[c + 2] + s.z : 0.f);
            o[3] = (bf16)((c + 3 < BOUT) ? bb[c + 3] + s.w : 0.f);
            *(ushort4*)&Arow[c] = *(ushort4*)o;
        }
    } else if (b < 6784) {                // zero K-pad cols 896..1023 of H1b/H2b
        int idx = b - 6752;               // 0..31
        bf16* H = (idx < 16) ? H1b : H2b;
        int sub = idx & 15;
        int t = threadIdx.x;
        int row = sub * 32 + (t >> 4);
        int col = 896 + (t & 15) * 8;
        *(uint4*)&H[(size_t)row * 1024 + col] = uint4{0u, 0u, 0u, 0u};
    } else {                              // zero cosine accumulators
        for (int i = threadIdx.x; i < 768; i += 512) psums[i] = 0.f;
    }
}

// ---------------- GEMM0: 128x128xBK64, 512 thr, split-K=16 XCD-pinned, dbuf, swizzled, bf16 slabs ----
// 32 KB staged per iter buys 128 wave-MFMA; total L2 staging 160 MB. 8 waves in 2(m)x4(n).
// Swizzle: chunk c of row r at physical chunk c^(r&7) -> <=2-way bank aliasing (free).
__global__ __launch_bounds__(512) void gemm0_splitk(const bf16* __restrict__ A,
                                                    const bf16* __restrict__ Bt,
                                                    bf16* __restrict__ Cslab) {
    constexpr int K0 = K0A, KITERS = 10, BK = 64;
    __shared__ __align__(16) bf16 As[2][128 * BK];   // 16 KB each buf
    __shared__ __align__(16) bf16 Bs[2][128 * BK];   // 16 KB each buf
    const int bid = blockIdx.x;
    const int kp = bid & 15;                  // XCD = bid%8 hosts kp, kp+8 -> ~3.8 MB L2 footprint
    const int tile = bid >> 4;                // 0..31
    const int mt = tile & 3, nt = tile >> 2;  // 4 x 8
    const int tid = threadIdx.x, wave = tid >> 6, lane = tid & 63;
    const int wm = wave & 1, wn = wave >> 1;  // 2x4 wave grid: 64m x 32n per wave
    const int lrow = lane & 15, quad = lane >> 4;

    const bf16* Ag = A  + (size_t)(mt * 128) * K0 + kp * (KITERS * BK);
    const bf16* Bg = Bt + (size_t)(nt * 128) * K0 + kp * (KITERS * BK);

    auto stage = [&](int buf, int kk) {
        const int k = kk * BK;
        const int lr = lane >> 3;                      // lane's row within an 8-row group
        const int lch = lane & 7;
#pragma unroll
        for (int j = 0; j < 2; ++j) {                  // A: 128 rows in 2 calls/wave (8 rows/call)
            int row0 = j * 64 + wave * 8;
            int row = row0 + lr;
            int ch  = lch ^ (row & 7);
            gload_lds16(Ag + (size_t)row * K0 + k + ch * 8, &As[buf][row0 * BK]);
        }
#pragma unroll
        for (int j = 0; j < 2; ++j) {                  // B: 128 rows in 2 calls/wave
            int row0 = j * 64 + wave * 8;
            int row = row0 + lr;
            int ch  = lch ^ (row & 7);
            gload_lds16(Bg + (size_t)row * K0 + k + ch * 8, &Bs[buf][row0 * BK]);
        }
    };

    f32x4 acc[4][2] = {};
    stage(0, 0);
    for (int kk = 0; kk < KITERS; ++kk) {
        const int cur = kk & 1;
        __syncthreads();                      // buf[cur] drained (vmcnt0 at barrier)
        if (kk + 1 < KITERS) stage(cur ^ 1, kk + 1);  // prefetch overlaps compute
#pragma unroll
        for (int ks = 0; ks < 2; ++ks) {
            bf16x8 af[4], bfr[2];
            const int c = ks * 4 + quad;
#pragma unroll
            for (int im = 0; im < 4; ++im) {
                int r = wm * 64 + im * 16 + lrow;
                af[im] = *(const bf16x8*)&As[cur][r * BK + ((c ^ (r & 7)) << 3)];
            }
#pragma unroll
            for (int in = 0; in < 2; ++in) {
                int r = wn * 32 + in * 16 + lrow;
                bfr[in] = *(const bf16x8*)&Bs[cur][r * BK + ((c ^ (r & 7)) << 3)];
            }
#pragma unroll
            for (int im = 0; im < 4; ++im)
#pragma unroll
                for (int in = 0; in < 2; ++in)
                    acc[im][in] = __builtin_amdgcn_mfma_f32_16x16x32_bf16(af[im], bfr[in], acc[im][in], 0, 0, 0);
        }
    }
    // bf16 partial stores into this kp's slab — no atomics, no fences
    bf16* C = Cslab + (size_t)kp * (NSPEC * N00);
#pragma unroll
    for (int im = 0; im < 4; ++im) {
        int row0 = mt * 128 + wm * 64 + im * 16 + quad * 4;
#pragma unroll
        for (int in = 0; in < 2; ++in) {
            int col = nt * 128 + wn * 32 + in * 16 + lrow;
#pragma unroll
            for (int r = 0; r < 4; ++r)
                C[(size_t)(row0 + r) * N00 + col] = (bf16)acc[im][in][r];
        }
    }
}

// ---------------- reduce 16 bf16 slabs + bias + relu + bf16 cvt ----------------
__global__ __launch_bounds__(256) void reduce_bias_relu(const bf16* __restrict__ Cslab,
                                                        const float* __restrict__ b0,
                                                        bf16* __restrict__ H0b) {
    int idx = blockIdx.x * 256 + threadIdx.x;     // 65536 chunks of 8
    int r = idx >> 7, c = (idx & 127) * 8;
    float s[8] = {};
#pragma unroll
    for (int kp = 0; kp < KSPLIT0; ++kp) {
        bf16x8 v = *(const bf16x8*)&Cslab[(size_t)kp * (NSPEC * N00) + (size_t)r * N00 + c];
#pragma unroll
        for (int j = 0; j < 8; ++j) s[j] += (float)v[j];
    }
    bf16 o[8];
#pragma unroll
    for (int j = 0; j < 8; ++j)
        o[j] = (bf16)fmaxf(s[j] + ((c + j < 1000) ? b0[c + j] : 0.f), 0.f);
    *(uint4*)&H0b[(size_t)r * N00 + c] = *(uint4*)o;
}

// ---------------- tail GEMM: 32x32 tiles, 512 thr, BK=256, wave-split-K, dbuf, swizzled ----------------
template <bool LAST>
__global__ __launch_bounds__(512) void gemm_tail(const bf16* __restrict__ A,
                                                 const bf16* __restrict__ Bt,
                                                 const float* __restrict__ bias,
                                                 bf16* __restrict__ Ob,
                                                 float* __restrict__ psums,
                                                 int Nreal, int ntiles) {
    constexpr int BK = 256, KITERS = 4;
    __shared__ __align__(16) bf16 As[2][32 * BK];   // 16 KB each
    __shared__ __align__(16) bf16 Bs[2][32 * BK];
    __shared__ f32x4 xacc[4][64];                   // 4 KB cross-wave combine
    const int bid = blockIdx.x;
    const int mt = bid / ntiles, nt = bid % ntiles;
    const int tid = threadIdx.x, wave = tid >> 6, lane = tid & 63;
    const int g = wave >> 2, w2 = wave & 3;
    const int wm = w2 & 1, wn = w2 >> 1;
    const int lrow = lane & 15, quad = lane >> 4;

    const bf16* Ag = A  + (size_t)(mt * 32) * 1024;
    const bf16* Bg = Bt + (size_t)(nt * 32) * 1024;

    auto stage = [&](int buf, int kk) {
        const int k = kk * BK;
#pragma unroll
        for (int j = 0; j < 2; ++j) {
            int row0 = (wave + j * 8) * 2;             // wave-uniform; covers rows row0, row0+1
            int row = row0 + (lane >> 5);
            int ch  = (lane & 31) ^ (row & 31);        // swizzled source chunk (32 chunks/row)
            gload_lds16(Ag + (size_t)row * 1024 + k + ch * 8, &As[buf][row0 * BK]);
            gload_lds16(Bg + (size_t)row * 1024 + k + ch * 8, &Bs[buf][row0 * BK]);
        }
    };

    f32x4 acc = {};
    stage(0, 0);
    for (int kk = 0; kk < KITERS; ++kk) {
        const int cur = kk & 1;
        __syncthreads();
        if (kk + 1 < KITERS) stage(cur ^ 1, kk + 1);
#pragma unroll
        for (int ks = 0; ks < 4; ++ks) {
            int ra = wm * 16 + lrow, rb = wn * 16 + lrow;
            int c = g * 16 + ks * 4 + quad;            // group g takes its k-half
            bf16x8 af  = *(const bf16x8*)&As[cur][ra * BK + ((c ^ (ra & 31)) << 3)];
            bf16x8 bfr = *(const bf16x8*)&Bs[cur][rb * BK + ((c ^ (rb & 31)) << 3)];
            acc = __builtin_amdgcn_mfma_f32_16x16x32_bf16(af, bfr, acc, 0, 0, 0);
        }
    }
    // combine the two k-halves
    __syncthreads();
    if (g == 1) xacc[w2][lane] = acc;
    __syncthreads();
    if (g == 0) {
        f32x4 o = xacc[w2][lane];
        acc[0] += o[0]; acc[1] += o[1]; acc[2] += o[2]; acc[3] += o[3];
        int row0 = mt * 32 + wm * 16 + quad * 4;
        int col  = nt * 32 + wn * 16 + lrow;
        if (!LAST) {
            float bv = (col < Nreal) ? bias[col] : 0.f;
#pragma unroll
            for (int r = 0; r < 4; ++r)
                Ob[(size_t)(row0 + r) * 1024 + col] = (bf16)fmaxf(acc[r] + bv, 0.f);
        } else {
            bool valid = (col < 400);
            float bv = valid ? bias[col] : 0.f;
            float v[4];
#pragma unroll
            for (int r = 0; r < 4; ++r) v[r] = valid ? (acc[r] + bv) : 0.f;
            int p0 = row0 >> 1;                        // pairs p0, p0+1 (row0 even)
            float sums[6] = {v[0] * v[1], v[0] * v[0], v[1] * v[1],
                             v[2] * v[3], v[2] * v[2], v[3] * v[3]};
#pragma unroll
            for (int off = 1; off < 16; off <<= 1)
#pragma unroll
                for (int s = 0; s < 6; ++s) sums[s] += __shfl_xor(sums[s], off);
            if (lrow == 0) {
#pragma unroll
                for (int s = 0; s < 3; ++s) {
                    atomicAdd(&psums[(p0 + 0) * 3 + s], sums[s]);
                    atomicAdd(&psums[(p0 + 1) * 3 + s], sums[3 + s]);
                }
            }
        }
    }
}

// ---------------- finalize cosine from psums ----------------
__global__ __launch_bounds__(256) void cosine_fin(const float* __restrict__ psums,
                                                  float* __restrict__ out) {
    int t = threadIdx.x;
    float d  = psums[t * 3 + 0];
    float s1 = psums[t * 3 + 1];
    float s2 = psums[t * 3 + 2];
    float n1 = fmaxf(sqrtf(s1), 1e-6f);
    float n2 = fmaxf(sqrtf(s2), 1e-6f);
    out[t] = d / (n1 * n2);
}

extern "C" void kernel_launch(void* const* d_in, const int* in_sizes, int n_in,
                              void* d_out, int out_size, void* d_ws, size_t ws_size,
                              hipStream_t stream) {
    const float* mz    = (const float*)d_in[0];
    const float* inten = (const float*)d_in[1];
    const float* bw    = (const float*)d_in[2];
    const float* bb    = (const float*)d_in[3];
    const float* w0    = (const float*)d_in[4];
    const float* b0    = (const float*)d_in[5];
    const float* w1    = (const float*)d_in[6];
    const float* b1    = (const float*)d_in[7];
    const float* w2    = (const float*)d_in[8];
    const float* b2    = (const float*)d_in[9];
    const float* we    = (const float*)d_in[10];
    const float* be    = (const float*)d_in[11];
    float* out = (float*)d_out;

    char* ws = (char*)d_ws;
    size_t off = 0;
    auto alloc = [&](size_t bytes) { char* p = ws + off; off += (bytes + 255) & ~(size_t)255; return p; };
    bf16*  A     = (bf16*) alloc((size_t)NSPEC * K0A * 2);
    bf16*  B0t   = (bf16*) alloc((size_t)N00 * K0A * 2);
    bf16*  B1t   = (bf16*) alloc((size_t)896 * 1024 * 2);
    bf16*  B2t   = (bf16*) alloc((size_t)896 * 1024 * 2);
    bf16*  BEt   = (bf16*) alloc((size_t)448 * 1024 * 2);
    bf16*  Cslab = (bf16*) alloc((size_t)KSPLIT0 * NSPEC * N00 * 2);   // 16 MB
    bf16*  H0b   = (bf16*) alloc((size_t)NSPEC * 1024 * 2);
    bf16*  H1b   = (bf16*) alloc((size_t)NSPEC * 1024 * 2);
    bf16*  H2b   = (bf16*) alloc((size_t)NSPEC * 1024 * 2);
    float* psums = (float*)alloc(768 * 4);

    // 1: weight transposes + build_A + zero pads + zero psums
    prep_all<<<6785, 512, 0, stream>>>(mz, inten, bw, bb, w0, w1, w2, we,
                                       A, B0t, B1t, B2t, BEt, H1b, H2b, psums);
    // 2: big GEMM, 128x128 tiles, split-K=16 XCD-pinned, swizzled LDS, bf16 slab stores
    gemm0_splitk<<<512, 512, 0, stream>>>(A, B0t, Cslab);
    // 3: slab reduce + bias + relu + bf16 cvt
    reduce_bias_relu<<<256, 256, 0, stream>>>(Cslab, b0, H0b);
    // 4-5: tail GEMMs, wave-split-K (bias+relu+bf16 fused)
    gemm_tail<false><<<448, 512, 0, stream>>>(H0b, B1t, b1, H1b, nullptr, 800, 28);
    gemm_tail<false><<<448, 512, 0, stream>>>(H1b, B2t, b2, H2b, nullptr, 800, 28);
    // 6: last GEMM + cosine partials (plain atomics, no fences)
    gemm_tail<true ><<<224, 512, 0, stream>>>(H2b, BEt, be, nullptr, psums, 400, 14);
    // 7: finalize
    cosine_fin<<<1, 256, 0, stream>>>(psums, out);
}